// Round 1
// 369.549 us; speedup vs baseline: 1.1386x; 1.1386x over previous
//
#include <hip/hip_runtime.h>
#include <math.h>

#define NN 40000
#define HD 128
#define NE 640000
#define MINN 1e-15f
#define NSB 157     // ceil(NN/256) scan blocks
#define GB  2500    // NN/16 gemm blocks (16 rows/block, 1 wave/block)
#define RB1 80      // stage-1 stats reduction blocks

typedef __attribute__((ext_vector_type(8))) short bf16x8;
typedef __attribute__((ext_vector_type(4))) float f32x4;

__device__ __forceinline__ float red16(float v){
  v += __shfl_xor(v, 1, 64); v += __shfl_xor(v, 2, 64);
  v += __shfl_xor(v, 4, 64); v += __shfl_xor(v, 8, 64);
  return v;
}

__device__ __forceinline__ float bf2f(short h){
  return __uint_as_float(((unsigned)(unsigned short)h) << 16);
}
__device__ __forceinline__ short f2bf(float v){
  unsigned u = __float_as_uint(v);
  u += 0x7FFF + ((u >> 16) & 1);       // RNE
  return (short)(u >> 16);
}

// ---------------- CSR build ----------------
__global__ void zero_int_k(int* __restrict__ c, int n){
  int i = blockIdx.x*blockDim.x + threadIdx.x;
  if (i < n) c[i] = 0;
}

__global__ void hist_k(const int* __restrict__ dst, int* __restrict__ cnt, int ne){
  int i = blockIdx.x*blockDim.x + threadIdx.x;
  int st = gridDim.x*blockDim.x;
  for (; i < ne; i += st) atomicAdd(&cnt[dst[i]], 1);
}

__global__ __launch_bounds__(256) void scan1_k(const int* __restrict__ cnt,
    int* __restrict__ locpre, int* __restrict__ btot){
  __shared__ int s[256];
  int t = threadIdx.x;
  int idx = blockIdx.x*256 + t;
  int v = (idx < NN) ? cnt[idx] : 0;
  s[t] = v; __syncthreads();
  for (int off = 1; off < 256; off <<= 1){
    int x = (t >= off) ? s[t-off] : 0;
    __syncthreads(); s[t] += x; __syncthreads();
  }
  locpre[idx] = s[t] - v;
  if (t == 255) btot[blockIdx.x] = s[255];
}

__global__ __launch_bounds__(256) void scan2_k(const int* __restrict__ btot,
    int* __restrict__ boff, int* __restrict__ ptr){
  __shared__ int s[256];
  int t = threadIdx.x;
  int v = (t < NSB) ? btot[t] : 0;
  s[t] = v; __syncthreads();
  for (int off = 1; off < 256; off <<= 1){
    int x = (t >= off) ? s[t-off] : 0;
    __syncthreads(); s[t] += x; __syncthreads();
  }
  if (t < NSB) boff[t] = s[t] - v;
  if (t == NSB-1) ptr[NN] = s[t];
}

__global__ __launch_bounds__(256) void scan3_k(const int* __restrict__ locpre,
    const int* __restrict__ boff, int* __restrict__ ptr, int* __restrict__ fil){
  int idx = blockIdx.x*256 + threadIdx.x;
  if (idx < NN){
    int v = boff[blockIdx.x] + locpre[idx];
    ptr[idx] = v; fil[idx] = v;
  }
}

__global__ void fill_k(const int* __restrict__ src, const int* __restrict__ dst,
    int* __restrict__ fill, unsigned short* __restrict__ eidx, int ne){
  int i = blockIdx.x*blockDim.x + threadIdx.x;
  int st = gridDim.x*blockDim.x;
  for (; i < ne; i += st){
    int d = dst[i];
    int pos = atomicAdd(&fill[d], 1);
    eidx[pos] = (unsigned short)src[i];
  }
}

// gather accumulate macro: 8 bf16 cols from one uint4 row-chunk
#define GACC(A,V) \
  A[0] += __uint_as_float((V).x << 16); A[1] += __uint_as_float((V).x & 0xffff0000u); \
  A[2] += __uint_as_float((V).y << 16); A[3] += __uint_as_float((V).y & 0xffff0000u); \
  A[4] += __uint_as_float((V).z << 16); A[5] += __uint_as_float((V).z & 0xffff0000u); \
  A[6] += __uint_as_float((V).w << 16); A[7] += __uint_as_float((V).w & 0xffff0000u);

// ---------------- W prep (ALL 8 weights): split bf16 hi/lo, MFMA B-fragment order ----
__global__ __launch_bounds__(256) void prepw_all_k(const float* __restrict__ fc0_w,
    const float* __restrict__ w1, const float* __restrict__ w2,
    const float* __restrict__ fco_w, bf16x8* __restrict__ bhi, bf16x8* __restrict__ blo){
  int widx = blockIdx.x >> 3;
  const float* W;
  if (widx == 0)      W = fc0_w;
  else if (widx <= 3) W = w1 + (size_t)(widx-1)*HD*HD;
  else if (widx <= 6) W = w2 + (size_t)(widx-4)*HD*HD;
  else                W = fco_w;
  int f = (blockIdx.x & 7)*256 + threadIdx.x;   // 0..2047 within slot
  int lane = f & 63;
  int ct = (f >> 6) & 7;
  int ks = f >> 9;
  int n  = ct*16 + (lane & 15);
  int k0 = ks*32 + (lane >> 4)*8;
  bf16x8 hv, lv;
  #pragma unroll
  for (int j = 0; j < 8; ++j){
    float v = W[n*HD + k0 + j];
    short hh = f2bf(v);
    short ll = f2bf(v - bf2f(hh));
    hv[j] = hh; lv[j] = ll;
  }
  bhi[widx*2048 + f] = hv; blo[widx*2048 + f] = lv;
}

// ---------------- MFMA GEMM with fused pre/post ops ----------------
// 1 wave/block; wave tile = 16 rows x 128 cols; split-bf16 3-term MFMA; grid 2500.
// GATHER: A-tile = self(f32) + sum of neighbor rows (bf16 mirror), staged via LDS.
// ZSTEP:  full hyperbolic z-update fused into the epilogue (acc holds new h rows).
template<bool GATHER, bool RELU, bool BN_IN, bool XH_IN, bool NORM_OUT,
         bool STATS, bool WRITE_HB, bool ZINIT, bool WRITE_OUT,
         bool ZSTEP, bool ZFIRST>
__global__ __launch_bounds__(64) void mgemm_k(const float* __restrict__ A,
    const bf16x8* __restrict__ bhi, const bf16x8* __restrict__ blo,
    const float* __restrict__ bias, const float* __restrict__ scale,
    const float* __restrict__ shift, float* __restrict__ out,
    unsigned short* __restrict__ hbout, float* __restrict__ part,
    float* __restrict__ zout, float scaling,
    const float* __restrict__ zpin, const float* __restrict__ zcin,
    const float* __restrict__ pvec,
    const uint4* __restrict__ hb4, const int* __restrict__ gptr,
    const unsigned short* __restrict__ eidx)
{
  const int lane = threadIdx.x;
  const int l15 = lane & 15, kg = lane >> 4;
  const long rb = (long)blockIdx.x*16;   // 2500*16 = 40000 exact

  // ---- A rows into av[ks][j]: row rb+l15, cols ks*32+kg*8 .. +8 ----
  float av[4][8];
  if constexpr (GATHER){
    // LDS tile padded to 132 floats/row: stride 132 dw == 4 (mod 32) banks ->
    // uniform bank load for both the float4 writes and the b128 fragment reads.
    __shared__ float tl[16*132];
    const int grp = kg, l = l15;         // 4 groups x 16 lanes; 4 nodes/group
    #pragma unroll
    for (int s = 0; s < 4; ++s){
      const int r = grp*4 + s;
      const long node = rb + r;
      int beg = gptr[node], end = gptr[node+1];
      const float4* selfp = (const float4*)(A + node*HD) + l*2;
      float4 s0 = selfp[0], s1 = selfp[1];
      float ga[8] = {s0.x,s0.y,s0.z,s0.w,s1.x,s1.y,s1.z,s1.w};
      int e = beg;
      for (; e + 4 <= end; e += 4){
        int i0 = eidx[e], i1 = eidx[e+1], i2 = eidx[e+2], i3 = eidx[e+3];
        uint4 v0 = hb4[(long)i0*16 + l];
        uint4 v1 = hb4[(long)i1*16 + l];
        uint4 v2 = hb4[(long)i2*16 + l];
        uint4 v3 = hb4[(long)i3*16 + l];
        GACC(ga,v0) GACC(ga,v1) GACC(ga,v2) GACC(ga,v3)
      }
      for (; e < end; ++e){
        uint4 v = hb4[(long)eidx[e]*16 + l];
        GACC(ga,v)
      }
      float4* tp = (float4*)(tl + r*132 + l*8);
      float4 o0 = {ga[0],ga[1],ga[2],ga[3]};
      float4 o1 = {ga[4],ga[5],ga[6],ga[7]};
      tp[0] = o0; tp[1] = o1;
    }
    __syncthreads();
    #pragma unroll
    for (int ks = 0; ks < 4; ++ks){
      const float* ap = tl + l15*132 + ks*32 + kg*8;
      float4 a0 = *(const float4*)ap;
      float4 a1 = *(const float4*)(ap + 4);
      av[ks][0]=a0.x; av[ks][1]=a0.y; av[ks][2]=a0.z; av[ks][3]=a0.w;
      av[ks][4]=a1.x; av[ks][5]=a1.y; av[ks][6]=a1.z; av[ks][7]=a1.w;
    }
  } else {
    #pragma unroll
    for (int ks = 0; ks < 4; ++ks){
      const float* ap = A + (rb + l15)*HD + ks*32 + kg*8;
      float4 a0 = *(const float4*)ap;
      float4 a1 = *(const float4*)(ap + 4);
      av[ks][0]=a0.x; av[ks][1]=a0.y; av[ks][2]=a0.z; av[ks][3]=a0.w;
      av[ks][4]=a1.x; av[ks][5]=a1.y; av[ks][6]=a1.z; av[ks][7]=a1.w;
    }
  }

  if (BN_IN){
    #pragma unroll
    for (int ks = 0; ks < 4; ++ks){
      const int k0 = ks*32 + kg*8;
      float4 s0 = *(const float4*)(scale + k0);
      float4 s1 = *(const float4*)(scale + k0 + 4);
      float4 h0 = *(const float4*)(shift + k0);
      float4 h1 = *(const float4*)(shift + k0 + 4);
      float sc[8] = {s0.x,s0.y,s0.z,s0.w,s1.x,s1.y,s1.z,s1.w};
      float sh[8] = {h0.x,h0.y,h0.z,h0.w,h1.x,h1.y,h1.z,h1.w};
      #pragma unroll
      for (int j = 0; j < 8; ++j)
        av[ks][j] = fmaf(av[ks][j], sc[j], sh[j]);
    }
  }
  if (XH_IN){
    float ss = 0.f;
    #pragma unroll
    for (int ks = 0; ks < 4; ++ks)
      #pragma unroll
      for (int j = 0; j < 8; ++j)
        ss = fmaf(av[ks][j], av[ks][j], ss);
    ss += __shfl_xor(ss, 16, 64);
    ss += __shfl_xor(ss, 32, 64);
    float n = sqrtf(ss);
    float yn = fmaxf(n, MINN);
    float c = fminf(yn, 1.0f);
    float at = 0.5f*logf((1.0f + c)/(1.0f - c));
    float scx = at / yn;
    #pragma unroll
    for (int ks = 0; ks < 4; ++ks)
      #pragma unroll
      for (int j = 0; j < 8; ++j)
        av[ks][j] *= scx;
  }

  f32x4 acc[8];
  #pragma unroll
  for (int ct = 0; ct < 8; ++ct){
    acc[ct][0]=0.f; acc[ct][1]=0.f; acc[ct][2]=0.f; acc[ct][3]=0.f;
  }
  // ---- split + MFMA ----
  #pragma unroll
  for (int ks = 0; ks < 4; ++ks){
    bf16x8 ah, al;
    #pragma unroll
    for (int j = 0; j < 8; ++j){
      float v = av[ks][j];
      short hh = f2bf(v);
      short ll = f2bf(v - bf2f(hh));
      ah[j] = hh; al[j] = ll;
    }
    #pragma unroll
    for (int ct = 0; ct < 8; ++ct){
      bf16x8 bh = bhi[(ks*8 + ct)*64 + lane];
      bf16x8 bl = blo[(ks*8 + ct)*64 + lane];
      acc[ct] = __builtin_amdgcn_mfma_f32_16x16x32_bf16(ah, bh, acc[ct], 0, 0, 0);
      acc[ct] = __builtin_amdgcn_mfma_f32_16x16x32_bf16(al, bh, acc[ct], 0, 0, 0);
      acc[ct] = __builtin_amdgcn_mfma_f32_16x16x32_bf16(ah, bl, acc[ct], 0, 0, 0);
    }
  }
  // bias + relu
  #pragma unroll
  for (int ct = 0; ct < 8; ++ct){
    float bb = bias[ct*16 + l15];
    #pragma unroll
    for (int q = 0; q < 4; ++q){
      float v = acc[ct][q] + bb;
      if (RELU) v = fmaxf(v, 0.f);
      acc[ct][q] = v;
    }
  }
  if (NORM_OUT){
    float ss[4] = {0.f,0.f,0.f,0.f};
    #pragma unroll
    for (int ct = 0; ct < 8; ++ct)
      #pragma unroll
      for (int q = 0; q < 4; ++q)
        ss[q] = fmaf(acc[ct][q], acc[ct][q], ss[q]);
    #pragma unroll
    for (int q = 0; q < 4; ++q){
      #pragma unroll
      for (int m = 1; m < 16; m <<= 1) ss[q] += __shfl_xor(ss[q], m, 64);
      ss[q] = 1.0f / fmaxf(sqrtf(ss[q]), 1e-12f);
    }
    #pragma unroll
    for (int ct = 0; ct < 8; ++ct)
      #pragma unroll
      for (int q = 0; q < 4; ++q)
        acc[ct][q] *= ss[q];
  }

  if (STATS){
    #pragma unroll
    for (int ct = 0; ct < 8; ++ct){
      float s = 0.f, q2 = 0.f;
      #pragma unroll
      for (int q = 0; q < 4; ++q){
        float v = acc[ct][q];
        s += v; q2 = fmaf(v, v, q2);
      }
      s  += __shfl_xor(s, 16, 64);  s  += __shfl_xor(s, 32, 64);
      q2 += __shfl_xor(q2, 16, 64); q2 += __shfl_xor(q2, 32, 64);
      if (kg == 0){
        part[blockIdx.x*256 + ct*16 + l15]       = s;
        part[blockIdx.x*256 + 128 + ct*16 + l15] = q2;
      }
    }
  }

  if (ZINIT){
    #pragma unroll
    for (int q = 0; q < 4; ++q){
      float ss = 0.f;
      #pragma unroll
      for (int ct = 0; ct < 8; ++ct)
        ss = fmaf(acc[ct][q], acc[ct][q], ss);
      ss += __shfl_xor(ss, 1, 64); ss += __shfl_xor(ss, 2, 64);
      ss += __shfl_xor(ss, 4, 64); ss += __shfl_xor(ss, 8, 64);
      float sc2 = scaling / sqrtf(ss);
      long row = rb + kg*4 + q;
      #pragma unroll
      for (int ct = 0; ct < 8; ++ct)
        zout[row*HD + ct*16 + l15] = acc[ct][q]*sc2;
    }
  }

  if constexpr (ZSTEP){
    // q_ = p/|p| is row-independent: compute once.
    float pv[8]; float pq = 0.f;
    #pragma unroll
    for (int ct = 0; ct < 8; ++ct){
      float t = pvec[ct*16 + l15];
      pv[ct] = t; pq = fmaf(t, t, pq);
    }
    pq = red16(pq);
    float qi = 1.0f / fmaxf(sqrtf(pq), MINN);
    #pragma unroll
    for (int ct = 0; ct < 8; ++ct) pv[ct] *= qi;

    #pragma unroll
    for (int q = 0; q < 4; ++q){
      const long row = rb + kg*4 + q;
      float zc[8], zp[8];
      #pragma unroll
      for (int ct = 0; ct < 8; ++ct) zc[ct] = zcin[row*HD + ct*16 + l15];
      if constexpr (!ZFIRST){
        #pragma unroll
        for (int ct = 0; ct < 8; ++ct) zp[ct] = zpin[row*HD + ct*16 + l15];
      } else {
        #pragma unroll
        for (int ct = 0; ct < 8; ++ct) zp[ct] = 0.f;
      }
      float hh = 0.f, cc = 0.f;
      #pragma unroll
      for (int ct = 0; ct < 8; ++ct){
        hh = fmaf(acc[ct][q], acc[ct][q], hh);
        cc = fmaf(zc[ct], zc[ct], cc);
      }
      hh = red16(hh); cc = red16(cc);
      float zs = scaling / sqrtf(hh);            // z_ch scale (matches old zstep)
      float di = 1.0f / fmaxf(cc, MINN);         // a = zcur * di
      float r2 = cc*di*di - 1.0f;                // sum(a^2) - 1
      float a[8], u[8]; float uu = 0.f;
      #pragma unroll
      for (int ct = 0; ct < 8; ++ct){
        a[ct] = zc[ct]*di;
        u[ct] = zp[ct] - a[ct];
        uu = fmaf(u[ct], u[ct], uu);
      }
      uu = red16(uu);
      float f = r2 / fmaxf(uu, MINN);
      float zpar[8]; float pn2 = 0.f;
      #pragma unroll
      for (int ct = 0; ct < 8; ++ct){
        zpar[ct] = fmaf(f, u[ct], a[ct]);
        pn2 = fmaf(zpar[ct], zpar[ct], pn2);
      }
      pn2 = red16(pn2);
      float pinv = 1.0f / fmaxf(sqrtf(pn2), MINN);
      float rv[8], zch[8]; float rz = 0.f, rr = 0.f;
      #pragma unroll
      for (int ct = 0; ct < 8; ++ct){
        zch[ct] = acc[ct][q]*zs;
        rv[ct] = pv[ct] - zpar[ct]*pinv;         // r = q_ - p_
        rz = fmaf(rv[ct], zch[ct], rz);
        rr = fmaf(rv[ct], rv[ct], rr);
      }
      rz = red16(rz); rr = red16(rr);
      float mm = rz / rr;
      float u2[8]; float uu2 = 0.f;
      #pragma unroll
      for (int ct = 0; ct < 8; ++ct){
        float z2 = fmaf(-2.0f*mm, rv[ct], zch[ct]);
        u2[ct] = z2 - a[ct];
        uu2 = fmaf(u2[ct], u2[ct], uu2);
      }
      uu2 = red16(uu2);
      float f2 = r2 / fmaxf(uu2, MINN);
      #pragma unroll
      for (int ct = 0; ct < 8; ++ct)
        zout[row*HD + ct*16 + l15] = fmaf(f2, u2[ct], a[ct]);
    }
  }

  if (WRITE_OUT || WRITE_HB){
    #pragma unroll
    for (int ct = 0; ct < 8; ++ct)
      #pragma unroll
      for (int q = 0; q < 4; ++q){
        float v = acc[ct][q];
        long row = rb + kg*4 + q;
        if (WRITE_OUT) out[row*HD + ct*16 + l15] = v;
        if (WRITE_HB && hbout) hbout[row*HD + ct*16 + l15] = (unsigned short)f2bf(v);
      }
  }
}

// ---------------- stats reduce stage 1: part[2500][256] -> part2[RB1][256] ----------------
__global__ __launch_bounds__(256) void red1_k(const float* __restrict__ part,
    float* __restrict__ part2){
  int c = threadIdx.x;
  float s = 0.f;
  for (int r = blockIdx.x; r < GB; r += RB1)
    s += part[(long)r*256 + c];
  part2[blockIdx.x*256 + c] = s;
}

// ---------------- BN finalize: reduce part2 -> scale/shift ----------------
__global__ __launch_bounds__(256) void bnfin_k(const float* __restrict__ part2,
    const float* __restrict__ g, const float* __restrict__ b,
    float* __restrict__ scale, float* __restrict__ shift){
  __shared__ float s2[256], q2[256];
  int c = threadIdx.x & 127, half = threadIdx.x >> 7;
  float s = 0.f, q = 0.f;
  for (int i = half; i < RB1; i += 2){
    s += part2[i*256 + c];
    q += part2[i*256 + 128 + c];
  }
  s2[threadIdx.x] = s; q2[threadIdx.x] = q;
  __syncthreads();
  if (half == 0){
    s = s2[c] + s2[c+128]; q = q2[c] + q2[c+128];
    float mu  = s * (1.0f/NN);
    float var = q * (1.0f/NN) - mu*mu;
    float istd = rsqrtf(var + 1e-5f);
    float scv = g[c]*istd;
    scale[c] = scv;
    shift[c] = fmaf(-mu, scv, b[c]);
  }
}

extern "C" void kernel_launch(void* const* d_in, const int* in_sizes, int n_in,
                              void* d_out, int out_size, void* d_ws, size_t ws_size,
                              hipStream_t stream) {
  const float* x       = (const float*)d_in[0];
  const int*   ei      = (const int*)  d_in[1];
  const float* fc0_w   = (const float*)d_in[2];
  const float* fc0_b   = (const float*)d_in[3];
  const float* w1      = (const float*)d_in[4];
  const float* b1      = (const float*)d_in[5];
  const float* gamma   = (const float*)d_in[6];
  const float* beta    = (const float*)d_in[7];
  const float* w2      = (const float*)d_in[8];
  const float* b2      = (const float*)d_in[9];
  const float* fco_w   = (const float*)d_in[10];
  const float* fco_b   = (const float*)d_in[11];
  const float* p       = (const float*)d_in[12];

  float* out = (float*)d_out;
  float* ws  = (float*)d_ws;

  float* h     = ws;                     // [NN*HD] f32
  float* zA    = h   + (size_t)NN*HD;
  float* zB    = zA  + (size_t)NN*HD;
  float* part  = zB  + (size_t)NN*HD;    // [GB*256]
  float* part2 = part + (size_t)GB*256;  // [RB1*256]
  float* scale = part2 + RB1*256;        // [128]
  float* shift = scale + 128;            // [128]
  bf16x8* bhi  = (bf16x8*)(shift + 128); // [8*2048]
  bf16x8* blo  = bhi + 8*2048;           // [8*2048]
  unsigned short* hb = (unsigned short*)(blo + 8*2048); // [NN*HD] bf16 mirror
  int* cnt     = (int*)(hb + (size_t)NN*HD);
  int* ptr     = cnt + NN;               // [NN+1]
  int* fil     = ptr + NN + 1;           // [NN]
  unsigned short* eidx = (unsigned short*)(fil + NN);   // [NE] (u16 src ids)
  int* locpre  = (int*)(eidx + NE);      // [NSB*256]
  int* btot    = locpre + NSB*256;       // [NSB]
  int* boff    = btot + NSB;             // [NSB]
  float* t = out;                        // reuse d_out as the w1-activation buffer

  const int* src = ei;
  const int* dst = ei + NE;
  const float scaling = tanhf(0.5f);

  // ---- CSR build (edges bucketed by dst) ----
  zero_int_k<<<(NN+255)/256, 256, 0, stream>>>(cnt, NN);
  hist_k<<<1024, 256, 0, stream>>>(dst, cnt, NE);
  scan1_k<<<NSB, 256, 0, stream>>>(cnt, locpre, btot);
  scan2_k<<<1, 256, 0, stream>>>(btot, boff, ptr);
  scan3_k<<<NSB, 256, 0, stream>>>(locpre, boff, ptr, fil);
  fill_k<<<1024, 256, 0, stream>>>(src, dst, fil, eidx, NE);

  // prep all 8 weight matrices (split-bf16, fragment order)
  prepw_all_k<<<64, 256, 0, stream>>>(fc0_w, w1, w2, fco_w, bhi, blo);

  // h = relu(x @ fc0_w^T + fc0_b)  + bf16 mirror + fused zinit (zcur=zB; zprev==0 implicit)
  mgemm_k<false,true,false,false,false,false,true,true,true,false,false>
      <<<GB, 64, 0, stream>>>(
      x, bhi, blo, fc0_b, nullptr, nullptr, h, hb, nullptr, zB, scaling,
      nullptr, nullptr, nullptr, nullptr, nullptr, nullptr);

  float* zprev = zA; float* zcur = zB;

  for (int i = 0; i < 3; ++i) {
    // t = relu((h + agg(h)) @ w1^T + b1), gather fused via LDS; column stats -> part
    mgemm_k<true,true,false,false,false,true,false,false,true,false,false>
        <<<GB, 64, 0, stream>>>(
        h, bhi + (1+i)*2048, blo + (1+i)*2048, b1 + i*HD, nullptr, nullptr, t,
        nullptr, part, nullptr, 0.f, nullptr, nullptr, nullptr,
        (const uint4*)hb, ptr, eidx);
    red1_k<<<RB1, 256, 0, stream>>>(part, part2);
    bnfin_k<<<1, 256, 0, stream>>>(part2, gamma + i*HD, beta + i*HD, scale, shift);
    // h = relu( BN(t) @ w2^T + b2 ) with fused hyperbolic z-step.
    // i<2: also write h (next gather self) + hb mirror; i==2: z-update only.
    if (i == 0)
      mgemm_k<false,true,true,false,false,false,true,false,true,true,true>
          <<<GB, 64, 0, stream>>>(
          t, bhi + 4*2048, blo + 4*2048, b2, scale, shift, h, hb, nullptr,
          zprev, scaling, zprev, zcur, p, nullptr, nullptr, nullptr);
    else if (i == 1)
      mgemm_k<false,true,true,false,false,false,true,false,true,true,false>
          <<<GB, 64, 0, stream>>>(
          t, bhi + 5*2048, blo + 5*2048, b2 + HD, scale, shift, h, hb, nullptr,
          zprev, scaling, zprev, zcur, p, nullptr, nullptr, nullptr);
    else
      mgemm_k<false,true,true,false,false,false,false,false,false,true,false>
          <<<GB, 64, 0, stream>>>(
          t, bhi + 6*2048, blo + 6*2048, b2 + 2*HD, scale, shift, h, nullptr, nullptr,
          zprev, scaling, zprev, zcur, p, nullptr, nullptr, nullptr);
    float* tmp = zprev; zprev = zcur; zcur = tmp;
  }

  // out = normalize( logmap0(z_cur) @ fc_out^T + fc_out_b )   (xh fused into A-load)
  mgemm_k<false,false,false,true,true,false,false,false,true,false,false>
      <<<GB, 64, 0, stream>>>(
      zcur, bhi + 7*2048, blo + 7*2048, fco_b, nullptr, nullptr, out,
      nullptr, nullptr, nullptr, 0.f, nullptr, nullptr, nullptr,
      nullptr, nullptr, nullptr);
}